// Round 13
// baseline (680.119 us; speedup 1.0000x reference)
//
#include <hip/hip_runtime.h>
#include <hip/hip_bf16.h>

#define N_NODES 8192
#define IN_FEAT 256
#define OUT_F   64
#define NHEAD   4
#define HF      256     // NHEAD*OUT_F
#define NEG     0.2f

typedef unsigned short u16;
typedef unsigned char  u8;
typedef unsigned int   u32;
typedef unsigned long long u64;
typedef _Float16 h2    __attribute__((ext_vector_type(2)));
typedef _Float16 half8 __attribute__((ext_vector_type(8)));
typedef __attribute__((ext_vector_type(4))) float f32x4;    // MFMA C/D

// ---------------------------------------------------------------------------
// K_wpack: fp16 MFMA-B fragments for the 256x512 weight block [W | PW^T].
// ---------------------------------------------------------------------------
__global__ __launch_bounds__(256) void k_wpack(const float* __restrict__ W,
                                               const float* __restrict__ PW,
                                               _Float16* __restrict__ W16B) {
    const int i = blockIdx.x * 256 + threadIdx.x;   // word 0..16383
    const int ks = i >> 11;            // k-step 0..7
    const int T  = (i >> 6) & 31;      // n-tile 0..31
    const int lane = i & 63;
    const int q  = lane >> 4, cc = lane & 15;
    const int n  = T * 16 + cc;
    const int k0 = ks * 32 + q * 8;
    union { _Float16 hh[8]; half8 v8; } o;
    #pragma unroll
    for (int e = 0; e < 8; ++e) {
        const int k = k0 + e;
        const float s = (n < 256) ? W[k * 256 + n]
                                  : PW[(size_t)(n - 256) * 256 + k];
        o.hh[e] = (_Float16)s;
    }
    *(half8*)(W16B + (size_t)i * 8) = o.v8;
}

// ---------------------------------------------------------------------------
// K_gemm (MFMA): block = 16 rows x 512 cols ([supp | proj]), 4 waves.
//   Stages inp fp32 -> fp16 LDS, MFMA main loop, fragment/proj epilogue,
//   zeroes its rows of anum/aden, and PACKS ITS 16 ADJACENCY ROWS into
//   straight-bit u32 words (adj HBM stream overlaps MFMA across blocks —
//   removes the serial adj read from k_attn entirely).
// ---------------------------------------------------------------------------
#define GROWS 16
__global__ __launch_bounds__(256) void k_gemm(
    const float* __restrict__ inp,      // [N][256] fp32
    const float* __restrict__ adj,      // [N][N] fp32
    const _Float16* __restrict__ W16B,  // [8][32][64][8] fp16 fragments
    const float* __restrict__ U,        // [256]
    const float* __restrict__ V,        // [256]
    const float* __restrict__ Bias,     // [256]
    const float* __restrict__ PB,       // [256]
    _Float16* __restrict__ suppB,       // [H][256][4][64][8] fp16 fragments
    float* __restrict__ f1,             // [H][N]
    float* __restrict__ f2,             // [H][N]
    float* __restrict__ outp,           // [N][256] proj + bias + proj_b
    u32*   __restrict__ gb32,           // [N][256] straight-bit flag words
    float* __restrict__ anum,           // [N][256]  zeroed here
    float* __restrict__ aden)           // [H][N]    zeroed here
{
    __shared__ __align__(16) _Float16 xl[GROWS][264];   // 528B rows
    const int n0  = blockIdx.x * GROWS;
    const int tid = threadIdx.x;
    const int wv  = tid >> 6, lane = tid & 63;
    const int col = lane & 15, quad = lane >> 4;

    // stage + convert: thread handles 16 floats of one row
    {
        const int r = tid >> 4, seg = tid & 15;
        const float* src = inp + (size_t)(n0 + r) * 256 + seg * 16;
        const float4 v0 = *(const float4*)(src);
        const float4 v1 = *(const float4*)(src + 4);
        const float4 v2 = *(const float4*)(src + 8);
        const float4 v3 = *(const float4*)(src + 12);
        union { _Float16 hh[8]; half8 v; } c0, c1;
        c0.hh[0] = (_Float16)v0.x; c0.hh[1] = (_Float16)v0.y;
        c0.hh[2] = (_Float16)v0.z; c0.hh[3] = (_Float16)v0.w;
        c0.hh[4] = (_Float16)v1.x; c0.hh[5] = (_Float16)v1.y;
        c0.hh[6] = (_Float16)v1.z; c0.hh[7] = (_Float16)v1.w;
        c1.hh[0] = (_Float16)v2.x; c1.hh[1] = (_Float16)v2.y;
        c1.hh[2] = (_Float16)v2.z; c1.hh[3] = (_Float16)v2.w;
        c1.hh[4] = (_Float16)v3.x; c1.hh[5] = (_Float16)v3.y;
        c1.hh[6] = (_Float16)v3.z; c1.hh[7] = (_Float16)v3.w;
        *(half8*)&xl[r][seg * 16]     = c0.v;
        *(half8*)&xl[r][seg * 16 + 8] = c1.v;
    }
    __syncthreads();

    f32x4 acc[8];
    #pragma unroll
    for (int t = 0; t < 8; ++t) acc[t] = (f32x4){0.f, 0.f, 0.f, 0.f};

    const int qo = quad * 8;
    #pragma unroll
    for (int ks = 0; ks < 8; ++ks) {
        const half8 af = *(const half8*)&xl[col][ks * 32 + qo];
        const _Float16* bb = W16B + ((size_t)(ks * 32 + wv * 8) * 64 + lane) * 8;
        #pragma unroll
        for (int t = 0; t < 8; ++t) {
            const half8 bw = *(const half8*)(bb + (size_t)t * 512);
            acc[t] = __builtin_amdgcn_mfma_f32_16x16x32_f16(af, bw, acc[t], 0, 0, 0);
        }
    }

    if (wv < 2) {
        // ---- supp columns: packed fragment stores ----
        const int jbg  = n0 >> 5;
        const int nlo  = n0 & 31;
        const int jq   = nlo + quad * 4;       // 4 consecutive j (one word)
        const int e0   = jq & 7;               // 0 or 4
        const int wrow = (jq >> 3) << 4;
        #pragma unroll
        for (int t = 0; t < 8; ++t) {
            const int cg = wv * 128 + t * 16 + col;   // 0..255
            const int h  = cg >> 6;
            const int tp = (cg >> 4) & 3;
            union { _Float16 hh[4]; u64 q; } pk;
            #pragma unroll
            for (int reg = 0; reg < 4; ++reg) pk.hh[reg] = (_Float16)acc[t][reg];
            const size_t word = ((size_t)(h * 256 + jbg) * 4 + tp) * 64 + wrow + col;
            *(u64*)(suppB + word * 8 + e0) = pk.q;
        }
        // ---- f1/f2 head dots (heads wv*2, wv*2+1) ----
        float s1a[4] = {0,0,0,0}, s2a[4] = {0,0,0,0};
        float s1b[4] = {0,0,0,0}, s2b[4] = {0,0,0,0};
        #pragma unroll
        for (int t = 0; t < 8; ++t) {
            const int cg = wv * 128 + t * 16 + col;
            const float uu = U[cg], vv = V[cg];
            #pragma unroll
            for (int reg = 0; reg < 4; ++reg) {
                if (t < 4) { s1a[reg] += acc[t][reg] * uu; s2a[reg] += acc[t][reg] * vv; }
                else       { s1b[reg] += acc[t][reg] * uu; s2b[reg] += acc[t][reg] * vv; }
            }
        }
        #pragma unroll
        for (int m = 1; m < 16; m <<= 1) {
            #pragma unroll
            for (int reg = 0; reg < 4; ++reg) {
                s1a[reg] += __shfl_xor(s1a[reg], m);
                s2a[reg] += __shfl_xor(s2a[reg], m);
                s1b[reg] += __shfl_xor(s1b[reg], m);
                s2b[reg] += __shfl_xor(s2b[reg], m);
            }
        }
        if (col == 0) {
            const int hA = wv * 2, hB = wv * 2 + 1;
            #pragma unroll
            for (int reg = 0; reg < 4; ++reg) {
                const int n = n0 + quad * 4 + reg;
                f1[hA * N_NODES + n] = s1a[reg];
                f2[hA * N_NODES + n] = s2a[reg];
                f1[hB * N_NODES + n] = s1b[reg];
                f2[hB * N_NODES + n] = s2b[reg];
            }
        }
    } else {
        // ---- proj columns ----
        #pragma unroll
        for (int t = 0; t < 8; ++t) {
            const int cg = (wv - 2) * 128 + t * 16 + col;
            const float bb2 = Bias[cg] + PB[cg];
            #pragma unroll
            for (int reg = 0; reg < 4; ++reg) {
                const int irow = quad * 4 + reg;
                outp[(size_t)(n0 + irow) * HF + cg] = acc[t][reg] + bb2;
            }
        }
    }

    // ---- zero this block's rows of anum/aden ----
    {
        const float4 z = {0.f, 0.f, 0.f, 0.f};
        float4* an = (float4*)(anum + (size_t)(n0 + (tid >> 4)) * HF + (tid & 15) * 16);
        an[0] = z; an[1] = z; an[2] = z; an[3] = z;
        if (tid < 64)
            aden[(size_t)(tid >> 4) * N_NODES + n0 + (tid & 15)] = 0.f;
    }

    // ---- pack adjacency rows n0..n0+15 (wave wv: 4 rows) ----
    // u32 word w of a row covers j=[32w,32w+32), bit b <-> j=32w+b.
    #pragma unroll 1
    for (int rr = 0; rr < 4; ++rr) {
        const int r = n0 + (wv << 2) + rr;
        const float* ar = adj + (size_t)r * N_NODES;
        u32* gr = gb32 + (size_t)r * 256;
        #pragma unroll
        for (int pi = 0; pi < 4; ++pi) {
            const float* as = ar + pi * 2048 + lane * 32;
            u32 wrd = 0;
            #pragma unroll
            for (int p = 0; p < 8; ++p) {
                const float4 a = *(const float4*)(as + p * 4);
                const u32 nib =
                    (u32)(a.x != 0.f)        | ((u32)(a.y != 0.f) << 1) |
                    ((u32)(a.z != 0.f) << 2) | ((u32)(a.w != 0.f) << 3);
                wrd |= nib << (p * 4);
            }
            gr[pi * 64 + lane] = wrd;
        }
    }
}

// ---------------------------------------------------------------------------
// K2: per-head f1 max + fp16 factored-exponential planes.
// ---------------------------------------------------------------------------
__global__ __launch_bounds__(256) void k_prep(const float* __restrict__ f1,
                                              float* __restrict__ f1max,
                                              _Float16* __restrict__ EA16,
                                              _Float16* __restrict__ EB16) {
    __shared__ float red[256];
    const int h = blockIdx.x;
    float m = -1e30f;
    for (int j = threadIdx.x; j < N_NODES; j += 256)
        m = fmaxf(m, f1[h * N_NODES + j]);
    red[threadIdx.x] = m;
    __syncthreads();
    for (int s = 128; s > 0; s >>= 1) {
        if (threadIdx.x < s) red[threadIdx.x] = fmaxf(red[threadIdx.x], red[threadIdx.x + s]);
        __syncthreads();
    }
    const float fm = red[0];
    if (threadIdx.x == 0) f1max[h] = fm;
    for (int j = threadIdx.x; j < N_NODES; j += 256) {
        const float d = f1[h * N_NODES + j] - fm;
        EA16[(size_t)h * N_NODES + j] = (_Float16)__expf(d);
        EB16[(size_t)h * N_NODES + j] = (_Float16)__expf(NEG * d);
    }
}

// ---------------------------------------------------------------------------
// K3: MFMA attention. JSPLIT=16 (grid 2048, JW=512, 5 blocks/CU): phase 1 is
//   a 4 KB L2 read of pre-packed flags (adj packing moved to k_gemm where it
//   overlaps MFMA). No HBM stream left in the j-loop: B-frags + EA/EB are
//   L2/L3-resident dense reads, flags come from LDS.
// ---------------------------------------------------------------------------
#define TI 64
#define NSUB 4
#define JSPLIT_G 16
#define JW (N_NODES / JSPLIT_G)     // 512-j window per block

__global__ __launch_bounds__(256, 5) void k_attn_mfma(
    const u32* __restrict__ gb32,       // [N][256] straight-bit flags
    const _Float16* __restrict__ suppB, // [H][256][4][64][8] fp16 fragments
    const _Float16* __restrict__ EA16,  // [H][N] fp16 exp(f1 - f1max)
    const _Float16* __restrict__ EB16,  // [H][N] fp16 exp(0.2*(f1 - f1max))
    const float* __restrict__ f2,       // [H][N]
    const float* __restrict__ f1max,    // [H]
    float* __restrict__ anum,           // [N][256] numerator accumulator
    float* __restrict__ aden)           // [H][N]   denominator accumulator
{
    __shared__ __align__(16) u8 abyte[TI][80];   // 5.1 KB (64B window + pad)

    const int itile = blockIdx.x >> 4;       // 0..127
    const int jwin  = blockIdx.x & 15;       // j-window
    const int i0    = itile * TI;
    const int J0    = jwin * JW;
    const int tid   = threadIdx.x;
    const int wv    = tid >> 6;              // wave = head
    const int lane  = tid & 63;
    const int col   = lane & 15;             // m (A) / n (B) / col (C)
    const int quad  = lane >> 4;

    // ---- Phase 1: stage flag window (4 KB): thread t -> 16B of one row ----
    {
        const int r  = tid >> 2;             // 0..63
        const int wi = tid & 3;              // 0..3
        const uint4 fw = *(const uint4*)(gb32 + (size_t)(i0 + r) * 256
                                         + (J0 >> 5) + wi * 4);
        *(uint4*)&abyte[r][wi * 16] = fw;
    }
    __syncthreads();

    // ---- Phase 2: fp16 flash j-loop, 4 i-subtiles ----
    const int h = wv;
    const float fm = f1max[h];
    h2 caH[NSUB], cbH[NSUB];
    float ls[NSUB];
    #pragma unroll
    for (int s = 0; s < NSUB; ++s) {
        const float f2i = f2[(size_t)h * N_NODES + i0 + s * 16 + col];
        const float g  = fm + f2i;
        const float mi = fmaxf(g, NEG * g);                 // leaky(g)
        const _Float16 ca = (_Float16)__expf(g - mi);
        const _Float16 cb = (_Float16)__expf(NEG * g - mi);
        caH[s][0] = ca; caH[s][1] = ca;
        cbH[s][0] = cb; cbH[s][1] = cb;
        ls[s] = 0.f;
    }
    const h2 ones = {(_Float16)1.0f, (_Float16)1.0f};

    const _Float16* gea = EA16 + (size_t)h * N_NODES + J0;
    const _Float16* geb = EB16 + (size_t)h * N_NODES + J0;
    const _Float16* sb  = suppB + (size_t)h * 524288          // h*256*2048
                        + (size_t)(J0 >> 5) * 2048 + lane * 8;

    f32x4 acc[NSUB][4];
    #pragma unroll
    for (int s = 0; s < NSUB; ++s)
        #pragma unroll
        for (int t = 0; t < 4; ++t)
            acc[s][t] = (f32x4){0.f, 0.f, 0.f, 0.f};

    const int qo = quad << 3;

    #pragma unroll 2
    for (int jb = 0; jb < JW; jb += 32) {
        const int jl = jb + qo;                             // lane's local j
        const _Float16* fp = sb + (size_t)(jb >> 5) * 2048; // fragment base
        const half8 bv0 = *(const half8*)(fp);
        const half8 bv1 = *(const half8*)(fp + 512);
        const half8 bv2 = *(const half8*)(fp + 1024);
        const half8 bv3 = *(const half8*)(fp + 1536);

        union { half8 v; h2 pr[4]; } ea, eb;
        ea.v = *(const half8*)(gea + jl);
        eb.v = *(const half8*)(geb + jl);
        const int wo = (jb >> 3) + quad;                    // flag byte offset

        #pragma unroll
        for (int s = 0; s < NSUB; ++s) {
            const unsigned gw = abyte[col + s * 16][wo];
            union { half8 v; unsigned w[4]; h2 pr[4]; } af;
            #pragma unroll
            for (int p = 0; p < 4; ++p) {
                const h2 pa = ea.pr[p] * caH[s];            // v_pk_mul_f16
                const h2 pb = eb.pr[p] * cbH[s];
                const h2 x  = __builtin_elementwise_max(pa, pb); // v_pk_max
                const unsigned mlo = (unsigned)((int)(gw << (31 - 2 * p)) >> 31) & 0x0000FFFFu;
                const unsigned mhi = (unsigned)((int)(gw << (30 - 2 * p)) >> 31) & 0xFFFF0000u;
                union { h2 hh; unsigned u; } xu;
                xu.hh = x;
                xu.u &= (mlo | mhi);
                af.w[p] = xu.u;
                ls[s] = __builtin_amdgcn_fdot2(xu.hh, ones, ls[s], false);
            }
            acc[s][0] = __builtin_amdgcn_mfma_f32_16x16x32_f16(af.v, bv0, acc[s][0], 0, 0, 0);
            acc[s][1] = __builtin_amdgcn_mfma_f32_16x16x32_f16(af.v, bv1, acc[s][1], 0, 0, 0);
            acc[s][2] = __builtin_amdgcn_mfma_f32_16x16x32_f16(af.v, bv2, acc[s][2], 0, 0, 0);
            acc[s][3] = __builtin_amdgcn_mfma_f32_16x16x32_f16(af.v, bv3, acc[s][3], 0, 0, 0);
        }
    }

    // denominators: reduce over quads; lane L holds sum for i = L&15
    #pragma unroll
    for (int s = 0; s < NSUB; ++s) {
        ls[s] += __shfl_xor(ls[s], 16);
        ls[s] += __shfl_xor(ls[s], 32);
    }
    if (quad == 0) {
        #pragma unroll
        for (int s = 0; s < NSUB; ++s)
            unsafeAtomicAdd(aden + (size_t)h * N_NODES + i0 + s * 16 + col, ls[s]);
    }

    // numerators: C layout col=lane&15, row=quad*4+reg
    #pragma unroll
    for (int s = 0; s < NSUB; ++s) {
        #pragma unroll
        for (int reg = 0; reg < 4; ++reg) {
            const int irow = (quad << 2) + reg;
            float* ap = anum + (size_t)(i0 + s * 16 + irow) * HF + (h << 6) + col;
            #pragma unroll
            for (int t = 0; t < 4; ++t)
                unsafeAtomicAdd(ap + (t << 4), acc[s][t][reg]);
        }
    }
}

// ---------------------------------------------------------------------------
// K4: out += anum / aden   (denominator > 0 guaranteed by self-loops)
// ---------------------------------------------------------------------------
__global__ __launch_bounds__(256) void k_fin(const float* __restrict__ anum,
                                             const float* __restrict__ aden,
                                             float* __restrict__ out) {
    const int c = threadIdx.x;
    const int h = c >> 6;
    #pragma unroll
    for (int rr = 0; rr < 4; ++rr) {
        const int n = blockIdx.x * 4 + rr;
        out[(size_t)n * HF + c] += anum[(size_t)n * HF + c]
                                 / aden[(size_t)h * N_NODES + n];
    }
}

// ---------------------------------------------------------------------------
extern "C" void kernel_launch(void* const* d_in, const int* in_sizes, int n_in,
                              void* d_out, int out_size, void* d_ws, size_t ws_size,
                              hipStream_t stream) {
    const float* inp  = (const float*)d_in[0];  // [8192,256]
    const float* adj  = (const float*)d_in[1];  // [8192,8192]
    const float* W    = (const float*)d_in[2];  // [256,256]
    const float* U    = (const float*)d_in[3];  // [4,64,1]
    const float* V    = (const float*)d_in[4];  // [4,64,1]
    const float* Bias = (const float*)d_in[5];  // [1,256]
    const float* PW   = (const float*)d_in[6];  // [256,256]
    const float* PB   = (const float*)d_in[7];  // [256]
    float* out = (float*)d_out;                 // [8192,256] fp32

    char* ws = (char*)d_ws;
    _Float16* suppB = (_Float16*)(ws);                           // 4 MiB
    float* f1    = (float*)(ws + (4u << 20));                    // 128 KiB
    float* f2    = (float*)(ws + (4u << 20) + (128u << 10));     // 128 KiB
    float* f1mx  = (float*)(ws + (4u << 20) + (256u << 10));     // 64 B
    _Float16* EA16 = (_Float16*)(ws + (4u << 20) + (576u << 10));// 64 KiB
    _Float16* EB16 = (_Float16*)(ws + (4u << 20) + (704u << 10));// 64 KiB
    float* aden  = (float*)(ws + (4u << 20) + (832u << 10));     // 128 KiB
    u32*   gb32  = (u32*)(ws + (8u << 20));                      // 8 MiB
    _Float16* W16B = (_Float16*)(ws + (20u << 20));              // 256 KiB
    float* anum  = (float*)(ws + (24u << 20));                   // 8 MiB

    k_wpack<<<  64, 256, 0, stream>>>(W, PW, W16B);
    k_gemm <<< 512, 256, 0, stream>>>(inp, adj, W16B, U, V, Bias, PB,
                                      suppB, f1, f2, out, gb32, anum, aden);
    k_prep <<<NHEAD, 256, 0, stream>>>(f1, f1mx, EA16, EB16);
    k_attn_mfma<<<(N_NODES / TI) * JSPLIT_G, 256, 0, stream>>>(
        gb32, suppB, EA16, EB16, f2, f1mx, anum, aden);
    k_fin  <<<N_NODES / 4, 256, 0, stream>>>(anum, aden, out);
}

// Round 14
// 452.583 us; speedup vs baseline: 1.5027x; 1.5027x over previous
//
#include <hip/hip_runtime.h>
#include <hip/hip_bf16.h>

#define N_NODES 8192
#define IN_FEAT 256
#define OUT_F   64
#define NHEAD   4
#define HF      256     // NHEAD*OUT_F
#define NEG     0.2f

typedef unsigned short u16;
typedef unsigned char  u8;
typedef unsigned int   u32;
typedef unsigned long long u64;
typedef _Float16 h2    __attribute__((ext_vector_type(2)));
typedef _Float16 half8 __attribute__((ext_vector_type(8)));
typedef __attribute__((ext_vector_type(4))) float f32x4;    // MFMA C/D

// ---------------------------------------------------------------------------
// K_wpack: fp16 MFMA-B fragments for the 256x512 weight block [W | PW^T].
// ---------------------------------------------------------------------------
__global__ __launch_bounds__(256) void k_wpack(const float* __restrict__ W,
                                               const float* __restrict__ PW,
                                               _Float16* __restrict__ W16B) {
    const int i = blockIdx.x * 256 + threadIdx.x;   // word 0..16383
    const int ks = i >> 11;            // k-step 0..7
    const int T  = (i >> 6) & 31;      // n-tile 0..31
    const int lane = i & 63;
    const int q  = lane >> 4, cc = lane & 15;
    const int n  = T * 16 + cc;
    const int k0 = ks * 32 + q * 8;
    union { _Float16 hh[8]; half8 v8; } o;
    #pragma unroll
    for (int e = 0; e < 8; ++e) {
        const int k = k0 + e;
        const float s = (n < 256) ? W[k * 256 + n]
                                  : PW[(size_t)(n - 256) * 256 + k];
        o.hh[e] = (_Float16)s;
    }
    *(half8*)(W16B + (size_t)i * 8) = o.v8;
}

// ---------------------------------------------------------------------------
// K_gemm (MFMA): block = 16 rows x 512 cols ([supp | proj]), 4 waves.
//   Stages inp fp32 -> fp16 LDS directly. Waves 0-1: suppB fragments +
//   f1/f2 reduce. Waves 2-3: proj cols -> out = acc + Bias + PB.
//   (No accumulator zeroing needed: attn writes partials, doesn't +=.)
// ---------------------------------------------------------------------------
#define GROWS 16
__global__ __launch_bounds__(256) void k_gemm(
    const float* __restrict__ inp,      // [N][256] fp32
    const _Float16* __restrict__ W16B,  // [8][32][64][8] fp16 fragments
    const float* __restrict__ U,        // [256]
    const float* __restrict__ V,        // [256]
    const float* __restrict__ Bias,     // [256]
    const float* __restrict__ PB,       // [256]
    _Float16* __restrict__ suppB,       // [H][256][4][64][8] fp16 fragments
    float* __restrict__ f1,             // [H][N]
    float* __restrict__ f2,             // [H][N]
    float* __restrict__ outp)           // [N][256] proj + bias + proj_b
{
    __shared__ __align__(16) _Float16 xl[GROWS][264];   // 528B rows
    const int n0  = blockIdx.x * GROWS;
    const int tid = threadIdx.x;
    const int wv  = tid >> 6, lane = tid & 63;
    const int col = lane & 15, quad = lane >> 4;

    // stage + convert: thread handles 16 floats of one row
    {
        const int r = tid >> 4, seg = tid & 15;
        const float* src = inp + (size_t)(n0 + r) * 256 + seg * 16;
        const float4 v0 = *(const float4*)(src);
        const float4 v1 = *(const float4*)(src + 4);
        const float4 v2 = *(const float4*)(src + 8);
        const float4 v3 = *(const float4*)(src + 12);
        union { _Float16 hh[8]; half8 v; } c0, c1;
        c0.hh[0] = (_Float16)v0.x; c0.hh[1] = (_Float16)v0.y;
        c0.hh[2] = (_Float16)v0.z; c0.hh[3] = (_Float16)v0.w;
        c0.hh[4] = (_Float16)v1.x; c0.hh[5] = (_Float16)v1.y;
        c0.hh[6] = (_Float16)v1.z; c0.hh[7] = (_Float16)v1.w;
        c1.hh[0] = (_Float16)v2.x; c1.hh[1] = (_Float16)v2.y;
        c1.hh[2] = (_Float16)v2.z; c1.hh[3] = (_Float16)v2.w;
        c1.hh[4] = (_Float16)v3.x; c1.hh[5] = (_Float16)v3.y;
        c1.hh[6] = (_Float16)v3.z; c1.hh[7] = (_Float16)v3.w;
        *(half8*)&xl[r][seg * 16]     = c0.v;
        *(half8*)&xl[r][seg * 16 + 8] = c1.v;
    }
    __syncthreads();

    f32x4 acc[8];
    #pragma unroll
    for (int t = 0; t < 8; ++t) acc[t] = (f32x4){0.f, 0.f, 0.f, 0.f};

    const int qo = quad * 8;
    #pragma unroll
    for (int ks = 0; ks < 8; ++ks) {
        const half8 af = *(const half8*)&xl[col][ks * 32 + qo];
        const _Float16* bb = W16B + ((size_t)(ks * 32 + wv * 8) * 64 + lane) * 8;
        #pragma unroll
        for (int t = 0; t < 8; ++t) {
            const half8 bw = *(const half8*)(bb + (size_t)t * 512);
            acc[t] = __builtin_amdgcn_mfma_f32_16x16x32_f16(af, bw, acc[t], 0, 0, 0);
        }
    }

    if (wv < 2) {
        // ---- supp columns: packed fragment stores ----
        const int jbg  = n0 >> 5;
        const int nlo  = n0 & 31;
        const int jq   = nlo + quad * 4;       // 4 consecutive j (one word)
        const int e0   = jq & 7;               // 0 or 4
        const int wrow = (jq >> 3) << 4;
        #pragma unroll
        for (int t = 0; t < 8; ++t) {
            const int cg = wv * 128 + t * 16 + col;   // 0..255
            const int h  = cg >> 6;
            const int tp = (cg >> 4) & 3;
            union { _Float16 hh[4]; u64 q; } pk;
            #pragma unroll
            for (int reg = 0; reg < 4; ++reg) pk.hh[reg] = (_Float16)acc[t][reg];
            const size_t word = ((size_t)(h * 256 + jbg) * 4 + tp) * 64 + wrow + col;
            *(u64*)(suppB + word * 8 + e0) = pk.q;
        }
        // ---- f1/f2 head dots (heads wv*2, wv*2+1) ----
        float s1a[4] = {0,0,0,0}, s2a[4] = {0,0,0,0};
        float s1b[4] = {0,0,0,0}, s2b[4] = {0,0,0,0};
        #pragma unroll
        for (int t = 0; t < 8; ++t) {
            const int cg = wv * 128 + t * 16 + col;
            const float uu = U[cg], vv = V[cg];
            #pragma unroll
            for (int reg = 0; reg < 4; ++reg) {
                if (t < 4) { s1a[reg] += acc[t][reg] * uu; s2a[reg] += acc[t][reg] * vv; }
                else       { s1b[reg] += acc[t][reg] * uu; s2b[reg] += acc[t][reg] * vv; }
            }
        }
        #pragma unroll
        for (int m = 1; m < 16; m <<= 1) {
            #pragma unroll
            for (int reg = 0; reg < 4; ++reg) {
                s1a[reg] += __shfl_xor(s1a[reg], m);
                s2a[reg] += __shfl_xor(s2a[reg], m);
                s1b[reg] += __shfl_xor(s1b[reg], m);
                s2b[reg] += __shfl_xor(s2b[reg], m);
            }
        }
        if (col == 0) {
            const int hA = wv * 2, hB = wv * 2 + 1;
            #pragma unroll
            for (int reg = 0; reg < 4; ++reg) {
                const int n = n0 + quad * 4 + reg;
                f1[hA * N_NODES + n] = s1a[reg];
                f2[hA * N_NODES + n] = s2a[reg];
                f1[hB * N_NODES + n] = s1b[reg];
                f2[hB * N_NODES + n] = s2b[reg];
            }
        }
    } else {
        // ---- proj columns ----
        #pragma unroll
        for (int t = 0; t < 8; ++t) {
            const int cg = (wv - 2) * 128 + t * 16 + col;
            const float bb2 = Bias[cg] + PB[cg];
            #pragma unroll
            for (int reg = 0; reg < 4; ++reg) {
                const int irow = quad * 4 + reg;
                outp[(size_t)(n0 + irow) * HF + cg] = acc[t][reg] + bb2;
            }
        }
    }
}

// ---------------------------------------------------------------------------
// K2: per-head f1 max + fp16 factored-exponential planes.
// ---------------------------------------------------------------------------
__global__ __launch_bounds__(256) void k_prep(const float* __restrict__ f1,
                                              float* __restrict__ f1max,
                                              _Float16* __restrict__ EA16,
                                              _Float16* __restrict__ EB16) {
    __shared__ float red[256];
    const int h = blockIdx.x;
    float m = -1e30f;
    for (int j = threadIdx.x; j < N_NODES; j += 256)
        m = fmaxf(m, f1[h * N_NODES + j]);
    red[threadIdx.x] = m;
    __syncthreads();
    for (int s = 128; s > 0; s >>= 1) {
        if (threadIdx.x < s) red[threadIdx.x] = fmaxf(red[threadIdx.x], red[threadIdx.x + s]);
        __syncthreads();
    }
    const float fm = red[0];
    if (threadIdx.x == 0) f1max[h] = fm;
    for (int j = threadIdx.x; j < N_NODES; j += 256) {
        const float d = f1[h * N_NODES + j] - fm;
        EA16[(size_t)h * N_NODES + j] = (_Float16)__expf(d);
        EB16[(size_t)h * N_NODES + j] = (_Float16)__expf(NEG * d);
    }
}

// ---------------------------------------------------------------------------
// K3: MFMA attention (round-12 structure: JSPLIT=8, fused adj pack, LDS =
//   flags only). CHANGE: no atomics — each (itile,jwin) block writes its
//   tile to private partials pnum[jwin]/pden[jwin] with plain coalesced
//   stores (streaming, no RMW amplification). k_fin combines.
// ---------------------------------------------------------------------------
#define TI 64
#define NSUB 4
#define JSPLIT_G 8
#define JW (N_NODES / JSPLIT_G)     // 1024-j window per block
#define ABW 132                     // bytes per row (128 + 4 pad)

__global__ __launch_bounds__(256, 4) void k_attn_mfma(
    const float* __restrict__ adj,      // [N][N] fp32
    const _Float16* __restrict__ suppB, // [H][256][4][64][8] fp16 fragments
    const _Float16* __restrict__ EA16,  // [H][N] fp16 exp(f1 - f1max)
    const _Float16* __restrict__ EB16,  // [H][N] fp16 exp(0.2*(f1 - f1max))
    const float* __restrict__ f2,       // [H][N]
    const float* __restrict__ f1max,    // [H]
    float* __restrict__ pnum,           // [JSPLIT][N][256] partial numerators
    float* __restrict__ pden)           // [JSPLIT][H][N]   partial denoms
{
    __shared__ __align__(4) u8 abyte[TI][ABW];   // 8.4 KB

    const int itile = blockIdx.x >> 3;       // 0..127
    const int jwin  = blockIdx.x & 7;        // j-window
    const int i0    = itile * TI;
    const int J0    = jwin * JW;
    const int wv    = threadIdx.x >> 6;      // wave = head
    const int lane  = threadIdx.x & 63;
    const int col   = lane & 15;             // m (A) / n (B) / col (C)
    const int quad  = lane >> 4;

    // ---- Phase 1: pack adj window bits (wave wv: 16 rows, 2 rows/pass) ----
    #pragma unroll
    for (int pass = 0; pass < 8; ++pass) {
        const int r = (wv << 4) + pass * 2 + (lane >> 5);
        const int w = lane & 31;
        const float* ar = adj + (size_t)(i0 + r) * N_NODES + J0 + w * 32;
        unsigned wrd = 0;
        #pragma unroll
        for (int p = 0; p < 8; ++p) {
            const float4 a = *(const float4*)(ar + p * 4);
            const unsigned nib =
                (unsigned)(a.x != 0.f)        | ((unsigned)(a.y != 0.f) << 1) |
                ((unsigned)(a.z != 0.f) << 2) | ((unsigned)(a.w != 0.f) << 3);
            wrd |= nib << (p * 4);
        }
        *(unsigned*)&abyte[r][w * 4] = wrd;
    }
    __syncthreads();

    // ---- Phase 2: fp16 flash j-loop, 4 i-subtiles ----
    const int h = wv;
    const float fm = f1max[h];
    h2 caH[NSUB], cbH[NSUB];
    float ls[NSUB];
    #pragma unroll
    for (int s = 0; s < NSUB; ++s) {
        const float f2i = f2[(size_t)h * N_NODES + i0 + s * 16 + col];
        const float g  = fm + f2i;
        const float mi = fmaxf(g, NEG * g);                 // leaky(g)
        const _Float16 ca = (_Float16)__expf(g - mi);
        const _Float16 cb = (_Float16)__expf(NEG * g - mi);
        caH[s][0] = ca; caH[s][1] = ca;
        cbH[s][0] = cb; cbH[s][1] = cb;
        ls[s] = 0.f;
    }
    const h2 ones = {(_Float16)1.0f, (_Float16)1.0f};

    const _Float16* gea = EA16 + (size_t)h * N_NODES + J0;
    const _Float16* geb = EB16 + (size_t)h * N_NODES + J0;
    const _Float16* sb  = suppB + (size_t)h * 524288          // h*256*2048
                        + (size_t)(J0 >> 5) * 2048 + lane * 8;

    f32x4 acc[NSUB][4];
    #pragma unroll
    for (int s = 0; s < NSUB; ++s)
        #pragma unroll
        for (int t = 0; t < 4; ++t)
            acc[s][t] = (f32x4){0.f, 0.f, 0.f, 0.f};

    const int qo = quad << 3;

    #pragma unroll 2
    for (int jb = 0; jb < JW; jb += 32) {
        const int jl = jb + qo;                             // lane's local j
        const _Float16* fp = sb + (size_t)(jb >> 5) * 2048; // fragment base
        const half8 bv0 = *(const half8*)(fp);
        const half8 bv1 = *(const half8*)(fp + 512);
        const half8 bv2 = *(const half8*)(fp + 1024);
        const half8 bv3 = *(const half8*)(fp + 1536);

        union { half8 v; h2 pr[4]; } ea, eb;
        ea.v = *(const half8*)(gea + jl);
        eb.v = *(const half8*)(geb + jl);
        const int wo = (jb >> 3) + quad;                    // flag byte offset

        #pragma unroll
        for (int s = 0; s < NSUB; ++s) {
            const unsigned gw = abyte[col + s * 16][wo];
            union { half8 v; unsigned w[4]; h2 pr[4]; } af;
            #pragma unroll
            for (int p = 0; p < 4; ++p) {
                const h2 pa = ea.pr[p] * caH[s];            // v_pk_mul_f16
                const h2 pb = eb.pr[p] * cbH[s];
                const h2 x  = __builtin_elementwise_max(pa, pb); // v_pk_max
                const unsigned mlo = (unsigned)((int)(gw << (31 - 2 * p)) >> 31) & 0x0000FFFFu;
                const unsigned mhi = (unsigned)((int)(gw << (30 - 2 * p)) >> 31) & 0xFFFF0000u;
                union { h2 hh; unsigned u; } xu;
                xu.hh = x;
                xu.u &= (mlo | mhi);
                af.w[p] = xu.u;
                ls[s] = __builtin_amdgcn_fdot2(xu.hh, ones, ls[s], false);
            }
            acc[s][0] = __builtin_amdgcn_mfma_f32_16x16x32_f16(af.v, bv0, acc[s][0], 0, 0, 0);
            acc[s][1] = __builtin_amdgcn_mfma_f32_16x16x32_f16(af.v, bv1, acc[s][1], 0, 0, 0);
            acc[s][2] = __builtin_amdgcn_mfma_f32_16x16x32_f16(af.v, bv2, acc[s][2], 0, 0, 0);
            acc[s][3] = __builtin_amdgcn_mfma_f32_16x16x32_f16(af.v, bv3, acc[s][3], 0, 0, 0);
        }
    }

    // denominators: reduce over quads; lane L holds sum for i = L&15
    #pragma unroll
    for (int s = 0; s < NSUB; ++s) {
        ls[s] += __shfl_xor(ls[s], 16);
        ls[s] += __shfl_xor(ls[s], 32);
    }
    if (quad == 0) {
        #pragma unroll
        for (int s = 0; s < NSUB; ++s)
            pden[((size_t)jwin * NHEAD + h) * N_NODES + i0 + s * 16 + col] = ls[s];
    }

    // numerators: plain streaming stores to this jwin's partial plane
    float* pn = pnum + (size_t)jwin * N_NODES * HF;
    #pragma unroll
    for (int s = 0; s < NSUB; ++s) {
        #pragma unroll
        for (int reg = 0; reg < 4; ++reg) {
            const int irow = (quad << 2) + reg;
            float* ap = pn + (size_t)(i0 + s * 16 + irow) * HF + (h << 6) + col;
            #pragma unroll
            for (int t = 0; t < 4; ++t)
                ap[t << 4] = acc[s][t][reg];
        }
    }
}

// ---------------------------------------------------------------------------
// K4: out += (sum_w pnum[w]) / (sum_w pden[w])   (fixed-order, deterministic)
// ---------------------------------------------------------------------------
__global__ __launch_bounds__(256) void k_fin(const float* __restrict__ pnum,
                                             const float* __restrict__ pden,
                                             float* __restrict__ out) {
    const int c = threadIdx.x;
    const int h = c >> 6;
    #pragma unroll
    for (int rr = 0; rr < 4; ++rr) {
        const int n = blockIdx.x * 4 + rr;
        float d = 0.f, s = 0.f;
        #pragma unroll
        for (int w = 0; w < JSPLIT_G; ++w) {
            d += pden[((size_t)w * NHEAD + h) * N_NODES + n];
            s += pnum[(size_t)w * N_NODES * HF + (size_t)n * HF + c];
        }
        out[(size_t)n * HF + c] += s / d;
    }
}

// ---------------------------------------------------------------------------
extern "C" void kernel_launch(void* const* d_in, const int* in_sizes, int n_in,
                              void* d_out, int out_size, void* d_ws, size_t ws_size,
                              hipStream_t stream) {
    const float* inp  = (const float*)d_in[0];  // [8192,256]
    const float* adj  = (const float*)d_in[1];  // [8192,8192]
    const float* W    = (const float*)d_in[2];  // [256,256]
    const float* U    = (const float*)d_in[3];  // [4,64,1]
    const float* V    = (const float*)d_in[4];  // [4,64,1]
    const float* Bias = (const float*)d_in[5];  // [1,256]
    const float* PW   = (const float*)d_in[6];  // [256,256]
    const float* PB   = (const float*)d_in[7];  // [256]
    float* out = (float*)d_out;                 // [8192,256] fp32

    char* ws = (char*)d_ws;
    _Float16* suppB = (_Float16*)(ws);                           // 4 MiB
    float* f1    = (float*)(ws + (4u << 20));                    // 128 KiB
    float* f2    = (float*)(ws + (4u << 20) + (128u << 10));     // 128 KiB
    float* f1mx  = (float*)(ws + (4u << 20) + (256u << 10));     // 64 B
    _Float16* EA16 = (_Float16*)(ws + (4u << 20) + (576u << 10));// 64 KiB
    _Float16* EB16 = (_Float16*)(ws + (4u << 20) + (704u << 10));// 64 KiB
    float* pden  = (float*)(ws + (8u << 20));                    // 1 MiB
    _Float16* W16B = (_Float16*)(ws + (20u << 20));              // 256 KiB
    float* pnum  = (float*)(ws + (32u << 20));                   // 64 MiB

    k_wpack<<<  64, 256, 0, stream>>>(W, PW, W16B);
    k_gemm <<< 512, 256, 0, stream>>>(inp, W16B, U, V, Bias, PB,
                                      suppB, f1, f2, out);
    k_prep <<<NHEAD, 256, 0, stream>>>(f1, f1mx, EA16, EB16);
    k_attn_mfma<<<(N_NODES / TI) * JSPLIT_G, 256, 0, stream>>>(
        adj, suppB, EA16, EB16, f2, f1mx, pnum, pden);
    k_fin  <<<N_NODES / 4, 256, 0, stream>>>(pnum, pden, out);
}